// Round 8
// baseline (207.335 us; speedup 1.0000x reference)
//
#include <hip/hip_runtime.h>

// MoE GLU MLP: E=8, D=1024, H=1024, K=2, N=2048 tokens, 4096 pairs.
// prep:  bucket(8 blk) + x->bf16 + W1^T->bf16  (critical path for gemm1)
// gemm1: x@W1 + SiLU-GLU, 64m x 64out-cols (z<8) ++ aux (z>=8): W2^T-cvt + out-zero
// gemm2: act@W2, 64m x 64n, fused gate-weighted atomic combine into out.
// R8 change: double-buffered LDS K-loop (1 barrier/iter, prefetch tile k+1 into
// the other buffer before computing tile k) in both GEMMs to hide staging latency.

typedef __bf16 bf16x8 __attribute__((ext_vector_type(8)));
typedef __bf16 bf16x4 __attribute__((ext_vector_type(4)));
typedef float  f32x4  __attribute__((ext_vector_type(4)));

#define NPAIR 4096
#define NTOK  2048
#define DDIM  1024
#define HDIM  1024
#define NEXP  8

// workspace layout (bytes)
#define ORDER_I   64                      // int index of order[] in wsi
#define XB_OFF    (24576)                 // bf16 x        [2048][1024]   4 MB
#define W1T_OFF   (XB_OFF + 4194304)      // bf16 W1^T  [8][2048][1024]  32 MB
#define W2T_OFF   (W1T_OFF + 33554432)    // bf16 W2^T  [8][1024][1024]  16 MB
#define ACT_OFF   (W2T_OFF + 16777216)    // bf16 act      [5120][1024] 10.5 MB

#define GLOAD_LDS16(g, l) \
    __builtin_amdgcn_global_load_lds( \
        (const __attribute__((address_space(1))) void*)(g), \
        (__attribute__((address_space(3))) void*)(l), 16, 0, 0)

// 64k x 64n transpose-convert tile: fp32 LDS bounce, float4 loads, bf16x8 (16B) stores
__device__ __forceinline__ void tcvt64(const float* __restrict__ s,
                                       __bf16* __restrict__ d,
                                       int R, int C, int k0, int c0,
                                       float (*tt)[65], int tid) {
#pragma unroll
    for (int p = 0; p < 4; p++) {
        int kr = p * 16 + (tid >> 4);
        int nc = (tid & 15) * 4;
        *(float4*)&tt[kr][nc] = *(const float4*)(s + (size_t)(k0 + kr) * C + c0 + nc);
    }
    __syncthreads();
#pragma unroll
    for (int p = 0; p < 2; p++) {
        int cid = p * 256 + tid;
        int n = cid >> 3, kc = cid & 7;
        bf16x8 o;
#pragma unroll
        for (int j = 0; j < 8; j++) o[j] = (__bf16)tt[kc * 8 + j][n];
        *(bf16x8*)(d + (size_t)(c0 + n) * R + k0 + kc * 8) = o;
    }
}

// ---------------- prep: W1-cvt (4096) + x-cvt (2048) + bucket (8) ----------------
__global__ __launch_bounds__(256) void prep_kernel(const float* __restrict__ x,
                                                   const float* __restrict__ W1,
                                                   const int* __restrict__ idx,
                                                   int* __restrict__ wsi,
                                                   __bf16* __restrict__ xb,
                                                   __bf16* __restrict__ w1t) {
    __shared__ float tt[64][65];
    __shared__ int cnt[NEXP];
    __shared__ int sbase, scur;
    const int b = blockIdx.x;
    const int tid = threadIdx.x;
    if (b < 4096) {
        int e = b >> 9, t2 = b & 511;
        int k0 = (t2 & 15) * 64, c0 = (t2 >> 4) * 64;
        tcvt64(W1 + (size_t)e * DDIM * 2 * HDIM, w1t + (size_t)e * 2 * HDIM * DDIM,
               DDIM, 2 * HDIM, k0, c0, tt, tid);
    } else if (b < 6144) {
        int i = (b - 4096) * 1024 + tid * 4;
        float4 v = *(const float4*)(x + i);
        bf16x4 o;
        o[0] = (__bf16)v.x; o[1] = (__bf16)v.y; o[2] = (__bf16)v.z; o[3] = (__bf16)v.w;
        *(bf16x4*)(xb + i) = o;
    } else {
        const int e = b - 6144;
        if (tid < NEXP) cnt[tid] = 0;
        if (tid == 0) scur = 0;
        __syncthreads();
        for (int i = tid; i < NPAIR; i += 256) atomicAdd(&cnt[idx[i] & 7], 1);
        __syncthreads();
        if (tid == 0) {
            int off = 0;
            for (int e2 = 0; e2 < NEXP; e2++) {
                if (e2 == e) { wsi[e] = cnt[e]; wsi[8 + e] = off; sbase = off; }
                off += (cnt[e2] + 127) & ~127;
            }
        }
        __syncthreads();
        for (int i = tid; i < NPAIR; i += 256) {
            if ((idx[i] & 7) == e) {
                int s = atomicAdd(&scur, 1);
                wsi[ORDER_I + sbase + s] = i;
            }
        }
    }
}

// ---------------- gemm1: 64m x 64 out-cols, dbuf LDS (z<8) + aux (z>=8) ----------------
__global__ __launch_bounds__(256) void gemm1_kernel(const __bf16* __restrict__ xb,
                                                    const __bf16* __restrict__ w1t,
                                                    const int* __restrict__ wsi,
                                                    __bf16* __restrict__ act,
                                                    const float* __restrict__ W2,
                                                    __bf16* __restrict__ w2t,
                                                    float* __restrict__ out) {
    // dbuf: buf b at smem + b*24576; As 8K, Bs 16K per buf. aux tcvt64 fp32[64][65]=16.6K fits.
    __shared__ __align__(16) char smem[49152];
    const int tid = threadIdx.x;
    const int z = blockIdx.z;

    if (z >= 8) {
        int aux = (z - 8) * 1024 + blockIdx.y * 16 + blockIdx.x;
        if (aux < 2048) {
            int e = aux >> 8, t2 = aux & 255;
            int k0 = (t2 & 15) * 64, c0 = (t2 >> 4) * 64;
            tcvt64(W2 + (size_t)e * HDIM * DDIM, w2t + (size_t)e * DDIM * HDIM,
                   HDIM, DDIM, k0, c0, (float (*)[65])smem, tid);
        } else if (aux < 2560) {
            int zb = aux - 2048;
            float4 z4 = {0.f, 0.f, 0.f, 0.f};
            int b4 = zb * 4096;
#pragma unroll
            for (int j = 0; j < 4; j++)
                *(float4*)(out + b4 + j * 1024 + tid * 4) = z4;
        }
        return;
    }

    const int e = z;
    const int cnt = wsi[e];
    const int m0 = blockIdx.y * 64;
    if (m0 >= cnt) return;
    const int base = wsi[8 + e];
    const int n0 = blockIdx.x * 64;
    const int* order = wsi + ORDER_I;
    const __bf16* w1e = w1t + (size_t)e * 2048 * 1024;

    const int lane = tid & 63, w = tid >> 6;
    const int lm = lane & 15, q = lane >> 4;
    const int wm = w & 1, wn = w >> 1;
    const int x7 = lm & 7;
    const int sw0 = (q ^ x7) * 16;
    const int sw1 = ((4 + q) ^ x7) * 16;

    const __bf16* ga[2];
    const __bf16* gb[4];
#pragma unroll
    for (int j = 0; j < 2; j++) {
        int c = j * 256 + tid;
        int r = c >> 3;
        int ks = ((c & 7) ^ (r & 7)) * 8;
        int m = m0 + r; if (m >= cnt) m = cnt - 1;
        int tok = order[base + m] >> 1;
        ga[j] = xb + (size_t)tok * DDIM + ks;
    }
#pragma unroll
    for (int j = 0; j < 4; j++) {
        int c = j * 256 + tid;
        int r = c >> 3;
        int ks = ((c & 7) ^ (r & 7)) * 8;
        int half = r >> 6, rr = r & 63;
        int rb = (rr < 32) ? (n0 + half * 32 + rr)
                           : (HDIM + n0 + half * 32 + (rr - 32));
        gb[j] = w1e + (size_t)rb * DDIM + ks;
    }

    f32x4 acc[2][4];
#pragma unroll
    for (int mt = 0; mt < 2; mt++)
#pragma unroll
        for (int nt = 0; nt < 4; nt++) acc[mt][nt] = (f32x4){0.f, 0.f, 0.f, 0.f};

    // prologue: tile 0 -> buf 0
#pragma unroll
    for (int j = 0; j < 2; j++) {
        int c = j * 256 + tid;
        GLOAD_LDS16(ga[j], smem + c * 16);
        ga[j] += 64;
    }
#pragma unroll
    for (int j = 0; j < 4; j++) {
        int c = j * 256 + tid;
        GLOAD_LDS16(gb[j], smem + 8192 + c * 16);
        gb[j] += 64;
    }

    const int nk = DDIM / 64;   // 16
    for (int k = 0; k < nk; k++) {
        __syncthreads();        // drains tile-k loads; prev compute's ds_reads already retired
        if (k + 1 < nk) {
            char* An = smem + ((k + 1) & 1) * 24576;
#pragma unroll
            for (int j = 0; j < 2; j++) {
                int c = j * 256 + tid;
                GLOAD_LDS16(ga[j], An + c * 16);
                ga[j] += 64;
            }
#pragma unroll
            for (int j = 0; j < 4; j++) {
                int c = j * 256 + tid;
                GLOAD_LDS16(gb[j], An + 8192 + c * 16);
                gb[j] += 64;
            }
        }
        const char* Ab = smem + (k & 1) * 24576;
        const char* Bb = Ab + 8192;
#pragma unroll
        for (int kh = 0; kh < 2; kh++) {
            const int sw = kh ? sw1 : sw0;
            bf16x8 af[2];
#pragma unroll
            for (int mt = 0; mt < 2; mt++)
                af[mt] = *(const bf16x8*)(Ab + (wm * 32 + mt * 16 + lm) * 128 + sw);
#pragma unroll
            for (int nt = 0; nt < 4; nt++) {
                bf16x8 bfr = *(const bf16x8*)(Bb + (wn * 64 + nt * 16 + lm) * 128 + sw);
#pragma unroll
                for (int mt = 0; mt < 2; mt++)
                    acc[mt][nt] = __builtin_amdgcn_mfma_f32_16x16x32_bf16(af[mt], bfr, acc[mt][nt], 0, 0, 0);
            }
        }
    }

#pragma unroll
    for (int mt = 0; mt < 2; mt++) {
        int mbase = m0 + wm * 32 + mt * 16 + q * 4;
#pragma unroll
        for (int ntp = 0; ntp < 2; ntp++) {
            int col = n0 + wn * 32 + ntp * 16 + lm;
#pragma unroll
            for (int r = 0; r < 4; r++) {
                int m = mbase + r;
                if (m < cnt) {
                    float h = acc[mt][ntp][r];
                    float g = acc[mt][ntp + 2][r];
                    float a = h * (g / (1.f + __expf(-g)));
                    act[(size_t)(base + m) * HDIM + col] = (__bf16)a;
                }
            }
        }
    }
}

// ---------------- gemm2: 64m x 64n, dbuf LDS, fused p-weighted atomic combine ----------------
__global__ __launch_bounds__(256) void gemm2_kernel(const __bf16* __restrict__ act,
                                                    const __bf16* __restrict__ w2t,
                                                    const int* __restrict__ wsi,
                                                    const float* __restrict__ p,
                                                    float* __restrict__ out) {
    const int e = blockIdx.z;
    const int cnt = wsi[e];
    const int m0 = blockIdx.y * 64;
    if (m0 >= cnt) return;
    const int base = wsi[8 + e];
    const int n0 = blockIdx.x * 64;
    const int* order = wsi + ORDER_I;
    const __bf16* w2e = w2t + (size_t)e * 1024 * 1024;

    // dbuf: buf b at smem + b*16384; As 8K, Bs 8K per buf
    __shared__ __align__(16) char smem[32768];

    const int tid = threadIdx.x;
    const int lane = tid & 63, w = tid >> 6;
    const int lm = lane & 15, q = lane >> 4;
    const int wm = w & 1, wn = w >> 1;
    const int x7 = lm & 7;
    const int sw0 = (q ^ x7) * 16;
    const int sw1 = ((4 + q) ^ x7) * 16;

    const __bf16* ga[2];
    const __bf16* gb[2];
#pragma unroll
    for (int j = 0; j < 2; j++) {
        int c = j * 256 + tid;
        int r = c >> 3;
        int ks = ((c & 7) ^ (r & 7)) * 8;
        ga[j] = act + (size_t)(base + m0 + r) * HDIM + ks;   // pad rows masked at epilogue
        gb[j] = w2e + (size_t)(n0 + r) * HDIM + ks;
    }

    f32x4 acc[2][2];
#pragma unroll
    for (int mt = 0; mt < 2; mt++)
#pragma unroll
        for (int nt = 0; nt < 2; nt++) acc[mt][nt] = (f32x4){0.f, 0.f, 0.f, 0.f};

    // prologue: tile 0 -> buf 0
#pragma unroll
    for (int j = 0; j < 2; j++) {
        int c = j * 256 + tid;
        GLOAD_LDS16(ga[j], smem + c * 16);
        GLOAD_LDS16(gb[j], smem + 8192 + c * 16);
        ga[j] += 64; gb[j] += 64;
    }

    const int nk = HDIM / 64;   // 16
    for (int k = 0; k < nk; k++) {
        __syncthreads();
        if (k + 1 < nk) {
            char* An = smem + ((k + 1) & 1) * 16384;
#pragma unroll
            for (int j = 0; j < 2; j++) {
                int c = j * 256 + tid;
                GLOAD_LDS16(ga[j], An + c * 16);
                GLOAD_LDS16(gb[j], An + 8192 + c * 16);
                ga[j] += 64; gb[j] += 64;
            }
        }
        const char* Ab = smem + (k & 1) * 16384;
        const char* Bb = Ab + 8192;
#pragma unroll
        for (int kh = 0; kh < 2; kh++) {
            const int sw = kh ? sw1 : sw0;
            bf16x8 af[2];
#pragma unroll
            for (int mt = 0; mt < 2; mt++)
                af[mt] = *(const bf16x8*)(Ab + (wm * 32 + mt * 16 + lm) * 128 + sw);
#pragma unroll
            for (int nt = 0; nt < 2; nt++) {
                bf16x8 bfr = *(const bf16x8*)(Bb + (wn * 32 + nt * 16 + lm) * 128 + sw);
#pragma unroll
                for (int mt = 0; mt < 2; mt++)
                    acc[mt][nt] = __builtin_amdgcn_mfma_f32_16x16x32_bf16(af[mt], bfr, acc[mt][nt], 0, 0, 0);
            }
        }
    }

    int pi[2][4];
    float pw[2][4];
#pragma unroll
    for (int mt = 0; mt < 2; mt++)
#pragma unroll
        for (int r = 0; r < 4; r++) {
            int gm = m0 + wm * 32 + mt * 16 + q * 4 + r;
            if (gm < cnt) {
                int pr = order[base + gm];
                pi[mt][r] = pr;
                pw[mt][r] = p[pr];
            } else pi[mt][r] = -1;
        }
#pragma unroll
    for (int mt = 0; mt < 2; mt++)
#pragma unroll
        for (int nt = 0; nt < 2; nt++) {
            int col = n0 + wn * 32 + nt * 16 + lm;
#pragma unroll
            for (int r = 0; r < 4; r++) {
                if (pi[mt][r] >= 0) {
                    int tok = pi[mt][r] >> 1;
                    atomicAdd(out + (size_t)tok * DDIM + col, pw[mt][r] * acc[mt][nt][r]);
                }
            }
        }
}

extern "C" void kernel_launch(void* const* d_in, const int* in_sizes, int n_in,
                              void* d_out, int out_size, void* d_ws, size_t ws_size,
                              hipStream_t stream) {
    (void)in_sizes; (void)n_in; (void)out_size; (void)ws_size;
    const float* x   = (const float*)d_in[0];
    const float* p   = (const float*)d_in[1];
    const int* eidx  = (const int*)d_in[2];
    const float* W1  = (const float*)d_in[3];
    const float* W2  = (const float*)d_in[4];
    float* out = (float*)d_out;

    char* ws = (char*)d_ws;
    int* wsi     = (int*)ws;
    __bf16* xb   = (__bf16*)(ws + XB_OFF);
    __bf16* w1t  = (__bf16*)(ws + W1T_OFF);
    __bf16* w2t  = (__bf16*)(ws + W2T_OFF);
    __bf16* act  = (__bf16*)(ws + ACT_OFF);

    prep_kernel<<<6152, 256, 0, stream>>>(x, W1, eidx, wsi, xb, w1t);
    gemm1_kernel<<<dim3(16, 64, 11), 256, 0, stream>>>(xb, w1t, wsi, act, W2, w2t, out);
    gemm2_kernel<<<dim3(16, 64, NEXP), 256, 0, stream>>>(act, w2t, wsi, p, out);
}